// Round 2
// baseline (1344.700 us; speedup 1.0000x reference)
//
#include <hip/hip_runtime.h>
#include <hip/hip_bf16.h>
#include <cstdint>
#include <cstddef>

constexpr int Nn = 4096;
constexpr float LRA = 0.2f;   // leaky relu slope

typedef __attribute__((ext_vector_type(8))) short bf16x8;
typedef __attribute__((ext_vector_type(4))) float f32x4;

__device__ __forceinline__ unsigned short f2bf(float x) {
  union { float f; unsigned u; } v; v.f = x;
  unsigned r = v.u + 0x7FFFu + ((v.u >> 16) & 1u);
  return (unsigned short)(r >> 16);
}
__device__ __forceinline__ float bf2f(unsigned short b) {
  union { unsigned u; float f; } v; v.u = ((unsigned)b) << 16; return v.f;
}

// h = prev[N,din] @ W[din,64]; writes htr (bf16 transposed [64][N]),
// f1 = h@av[:64], f2 = h@av[64:]. One wave per row, lane == out dim.
// Batched over heads via blockIdx.y.
__global__ __launch_bounds__(256) void k_hf4(
    const float* __restrict__ prev, int din,
    const float* __restrict__ Wb, size_t wstride,
    const float* __restrict__ avb, size_t avstride,
    unsigned short* __restrict__ htrb,
    float* __restrict__ f1b, float* __restrict__ f2b) {
  __shared__ float Wl[64 * 64];
  int h = blockIdx.y;
  const float* W  = Wb + (size_t)h * wstride;
  const float* av = avb + (size_t)h * avstride;
  unsigned short* htr = htrb + (size_t)h * 64 * Nn;
  int t = threadIdx.x;
  int r = __builtin_amdgcn_readfirstlane(blockIdx.x * 4 + (t >> 6));
  int d = t & 63;
  const float* pr = prev + (size_t)r * din;
  float acc = 0.f;
  for (int kb = 0; kb < din; kb += 64) {
    for (int i = t; i < 64 * 64; i += 256) Wl[i] = W[kb * 64 + i];
    __syncthreads();
    #pragma unroll 8
    for (int k = 0; k < 64; ++k) acc = fmaf(pr[kb + k], Wl[k * 64 + d], acc);
    __syncthreads();
  }
  htr[(size_t)d * Nn + r] = f2bf(acc);
  float p1 = acc * av[d];
  float p2 = acc * av[64 + d];
  #pragma unroll
  for (int off = 32; off; off >>= 1) {
    p1 += __shfl_down(p1, off);
    p2 += __shfl_down(p2, off);
  }
  if (d == 0) { f1b[h * Nn + r] = p1; f2b[h * Nn + r] = p2; }
}

// rank[k] = descending sort rank of f1[k] (stable by index);
// mj[j] = #{k: f1[k] > -f2[j]}. grid (32, nh); 8192 items/head.
__global__ __launch_bounds__(256) void k_rank4(
    const float* __restrict__ f1b, const float* __restrict__ f2b,
    int* __restrict__ rankb, int* __restrict__ mjb) {
  __shared__ __align__(16) float fl[Nn];
  int h = blockIdx.y;
  const float* f1 = f1b + (size_t)h * Nn;
  int t = threadIdx.x;
  for (int i = t; i < Nn; i += 256) fl[i] = f1[i];
  __syncthreads();
  int item = blockIdx.x * 256 + t;   // 0..8191
  const float4* fv = (const float4*)fl;
  if (item < Nn) {
    int k = item;
    float v = fl[k];
    int cnt = 0;
    #pragma unroll 4
    for (int i = 0; i < Nn / 4; ++i) {
      float4 w = fv[i];
      int ib = i * 4;
      cnt += (w.x > v || (w.x == v && ib < k)) ? 1 : 0;
      cnt += (w.y > v || (w.y == v && ib + 1 < k)) ? 1 : 0;
      cnt += (w.z > v || (w.z == v && ib + 2 < k)) ? 1 : 0;
      cnt += (w.w > v || (w.w == v && ib + 3 < k)) ? 1 : 0;
    }
    rankb[h * Nn + k] = cnt;
  } else {
    int j = item - Nn;
    float thr = -f2b[h * Nn + j];
    int cnt = 0;
    #pragma unroll 4
    for (int i = 0; i < Nn / 4; ++i) {
      float4 w = fv[i];
      cnt += (w.x > thr) ? 1 : 0;
      cnt += (w.y > thr) ? 1 : 0;
      cnt += (w.z > thr) ? 1 : 0;
      cnt += (w.w > thr) ? 1 : 0;
    }
    mjb[h * Nn + j] = cnt;
  }
}

// One block per row r; adj row read once into registers, then per head:
// scatter into sorted order, scan, s-pass via prefix lookup, softmax,
// write bf16 att row.
__global__ __launch_bounds__(256) void k_rows4(
    const float* __restrict__ adj, const int* __restrict__ rankb,
    const float* __restrict__ f1b, const float* __restrict__ f2b,
    const int* __restrict__ mjb, unsigned short* __restrict__ attb, int nh) {
  __shared__ float P0[Nn];
  __shared__ float P1[Nn];
  __shared__ float red[32];
  int t = threadIdx.x;
  int lane = t & 63;
  int wv = t >> 6;
  int r = blockIdx.x;
  const float* arow = adj + (size_t)r * Nn;
  float av[16];
  #pragma unroll
  for (int i = 0; i < 16; ++i) av[i] = arow[i * 256 + t];

  for (int h = 0; h < nh; ++h) {
    const int* rankg = rankb + (size_t)h * Nn;
    const float* f1 = f1b + (size_t)h * Nn;
    const float* f2 = f2b + (size_t)h * Nn;
    const int* mj = mjb + (size_t)h * Nn;
    unsigned short* att = attb + (size_t)h * Nn * Nn;
    __syncthreads();   // protect P0/P1/red from previous head
    #pragma unroll
    for (int i = 0; i < 16; ++i) {
      int k = i * 256 + t;
      int rk = rankg[k];
      P0[rk] = av[i];
      P1[rk] = av[i] * f1[k];
    }
    __syncthreads();
    // inclusive scan (thread-local 16 + wave scan + cross-wave)
    int base = t * 16;
    float a0[16], a1[16];
    #pragma unroll
    for (int i = 0; i < 16; ++i) { a0[i] = P0[base + i]; a1[i] = P1[base + i]; }
    #pragma unroll
    for (int i = 1; i < 16; ++i) { a0[i] += a0[i - 1]; a1[i] += a1[i - 1]; }
    float t0 = a0[15], t1 = a1[15];
    float s0 = t0, s1 = t1;
    #pragma unroll
    for (int off = 1; off < 64; off <<= 1) {
      float u0 = __shfl_up(s0, off);
      float u1 = __shfl_up(s1, off);
      if (lane >= off) { s0 += u0; s1 += u1; }
    }
    if (lane == 63) { red[wv] = s0; red[8 + wv] = s1; }
    __syncthreads();
    float w0 = 0.f, w1 = 0.f;
    for (int i = 0; i < wv; ++i) { w0 += red[i]; w1 += red[8 + i]; }
    float ex0 = (s0 - t0) + w0;
    float ex1 = (s1 - t1) + w1;
    #pragma unroll
    for (int i = 0; i < 16; ++i) { P0[base + i] = a0[i] + ex0; P1[base + i] = a1[i] + ex1; }
    __syncthreads();
    float S0 = P0[Nn - 1], S1 = P1[Nn - 1];
    // s[r,j] = a*(S1 + f2j*S0) + (1-a)*(P1[m-1] + f2j*P0[m-1])
    float sv[16];
    float mx = -3.0e38f;
    #pragma unroll
    for (int c = 0; c < 16; ++c) {
      int j = c * 256 + t;
      int mm = mj[j];
      float fj = f2[j];
      float pr0 = (mm > 0) ? P0[mm - 1] : 0.f;
      float pr1 = (mm > 0) ? P1[mm - 1] : 0.f;
      float s = LRA * fmaf(fj, S0, S1) + (1.f - LRA) * fmaf(fj, pr0, pr1);
      sv[c] = s;
      mx = fmaxf(mx, s);
    }
    #pragma unroll
    for (int off = 32; off; off >>= 1) mx = fmaxf(mx, __shfl_xor(mx, off));
    __syncthreads();
    if (lane == 0) red[wv] = mx;
    __syncthreads();
    mx = fmaxf(fmaxf(red[0], red[1]), fmaxf(red[2], red[3]));
    float pv[16];
    float sum = 0.f;
    #pragma unroll
    for (int c = 0; c < 16; ++c) { float p = __expf(sv[c] - mx); pv[c] = p; sum += p; }
    #pragma unroll
    for (int off = 32; off; off >>= 1) sum += __shfl_xor(sum, off);
    if (lane == 0) red[8 + wv] = sum;
    __syncthreads();
    float inv = 1.f / (red[8] + red[9] + red[10] + red[11]);
    unsigned short* orow = att + (size_t)r * Nn;
    #pragma unroll
    for (int c = 0; c < 16; ++c) orow[c * 256 + t] = f2bf(pv[c] * inv);
  }
}

// C[4096,NC] = A[4096,4096] @ B ; B transposed bf16 [NC][4096].
// AMODE 0: A bf16; 1: A f32->bf16; 2: A f32 split hi/lo (3-MFMA).
// Split-K=8 into Cpart[kc][4096][NC]. Batched over blockIdx.z.
template<int AMODE, int NC, bool BSPLIT>
__global__ __launch_bounds__(256) void k_gemm(
    const void* __restrict__ Ap, size_t astride,
    const unsigned short* __restrict__ Bthb,
    const unsigned short* __restrict__ Btlb, size_t bstride,
    float* __restrict__ Cpartb, size_t cstride) {
  constexpr int NT = NC / 16;
  int h = blockIdx.z;
  const unsigned short* Bth = Bthb + (size_t)h * bstride;
  const unsigned short* Btl = Btlb ? Btlb + (size_t)h * bstride : nullptr;
  float* Cpart = Cpartb + (size_t)h * cstride;
  int t = threadIdx.x;
  int wv = t >> 6, l = t & 63;
  int l15 = l & 15, lq = l >> 4;
  int row0 = blockIdx.x * 64 + wv * 16;
  int kc = blockIdx.y;
  f32x4 acc[NT];
  #pragma unroll
  for (int i = 0; i < NT; ++i) acc[i] = (f32x4){0.f, 0.f, 0.f, 0.f};
  int row = row0 + l15;
  int kb = kc * 512 + lq * 8;
  for (int k0 = 0; k0 < 512; k0 += 32) {
    int k = kb + k0;
    bf16x8 af, af2;
    if constexpr (AMODE == 0) {
      af = *(const bf16x8*)((const unsigned short*)Ap + (size_t)h * astride +
                            (size_t)row * Nn + k);
    } else {
      const float* fp = (const float*)Ap + (size_t)row * Nn + k;
      const float4 xa = *(const float4*)fp;
      const float4 xb = *(const float4*)(fp + 4);
      float xs[8] = {xa.x, xa.y, xa.z, xa.w, xb.x, xb.y, xb.z, xb.w};
      #pragma unroll
      for (int i = 0; i < 8; ++i) {
        unsigned short hb = f2bf(xs[i]);
        ((unsigned short*)&af)[i] = hb;
        if constexpr (AMODE == 2)
          ((unsigned short*)&af2)[i] = f2bf(xs[i] - bf2f(hb));
      }
    }
    #pragma unroll
    for (int ct = 0; ct < NT; ++ct) {
      bf16x8 bh = *(const bf16x8*)(Bth + (size_t)(ct * 16 + l15) * Nn + k);
      acc[ct] = __builtin_amdgcn_mfma_f32_16x16x32_bf16(af, bh, acc[ct], 0, 0, 0);
      if constexpr (BSPLIT) {
        bf16x8 bl = *(const bf16x8*)(Btl + (size_t)(ct * 16 + l15) * Nn + k);
        acc[ct] = __builtin_amdgcn_mfma_f32_16x16x32_bf16(af, bl, acc[ct], 0, 0, 0);
      }
      if constexpr (AMODE == 2)
        acc[ct] = __builtin_amdgcn_mfma_f32_16x16x32_bf16(af2, bh, acc[ct], 0, 0, 0);
    }
  }
  // D layout (m89-verified): col = lane&15, row = 4*(lane>>4)+reg
  #pragma unroll
  for (int ct = 0; ct < NT; ++ct) {
    #pragma unroll
    for (int q = 0; q < 4; ++q) {
      int rr = row0 + lq * 4 + q;
      int cc = ct * 16 + l15;
      Cpart[((size_t)kc * Nn + rr) * NC + cc] = acc[ct][q];
    }
  }
}

// sum split-K partials + epilogue (0 none, 1 elu, 2 relu); optional strided
// f32 write and/or transposed bf16 hi/lo planes. Batched over blockIdx.y.
template<int NC>
__global__ __launch_bounds__(256) void k_red4(
    const float* __restrict__ Cpartb, size_t cph,
    float* __restrict__ dst, int ldd, int coff0, int coffstep, int epi,
    unsigned short* __restrict__ oh, unsigned short* __restrict__ ol) {
  int h = blockIdx.y;
  const float* cp = Cpartb + (size_t)h * cph;
  int id = blockIdx.x * 256 + threadIdx.x;
  int r = id / NC, c = id % NC;
  float s = 0.f;
  #pragma unroll
  for (int kc = 0; kc < 8; ++kc) s += cp[((size_t)kc * Nn + r) * NC + c];
  if (epi == 1) s = (s > 0.f) ? s : expm1f(s);
  else if (epi == 2) s = fmaxf(s, 0.f);
  if (dst) dst[(size_t)r * ldd + coff0 + h * coffstep + c] = s;
  if (oh) {
    unsigned short hb = f2bf(s);
    oh[(size_t)c * Nn + r] = hb;
    if (ol) ol[(size_t)c * Nn + r] = f2bf(s - bf2f(hb));
  }
}

// fused: h1 = relu(sum partials); u = h1 @ l2w[64,32]; write ut bf16 [32][N]
__global__ __launch_bounds__(256) void k_redU(
    const float* __restrict__ Cpart, const float* __restrict__ W,
    unsigned short* __restrict__ ut) {
  __shared__ float hl[4][64];
  __shared__ float Wl[64 * 32];
  int t = threadIdx.x;
  for (int i = t; i < 64 * 32; i += 256) Wl[i] = W[i];
  int id = blockIdx.x * 256 + t;     // grid.x = 1024 -> 4 rows/block
  int r = id >> 6, c = id & 63;
  float s = 0.f;
  #pragma unroll
  for (int kc = 0; kc < 8; ++kc) s += Cpart[((size_t)kc * Nn + r) * 64 + c];
  hl[t >> 6][c] = fmaxf(s, 0.f);
  __syncthreads();
  if (t < 128) {
    int lr = t >> 5, d = t & 31;
    int row = blockIdx.x * 4 + lr;
    const float* hr = hl[lr];
    float acc = 0.f;
    #pragma unroll 8
    for (int k = 0; k < 64; ++k) acc = fmaf(hr[k], Wl[k * 32 + d], acc);
    ut[(size_t)d * Nn + row] = f2bf(acc);
  }
}

extern "C" void kernel_launch(void* const* d_in, const int* in_sizes, int n_in,
                              void* d_out, int out_size, void* d_ws, size_t ws_size,
                              hipStream_t stream) {
  (void)in_sizes; (void)n_in; (void)out_size; (void)ws_size;
  const float* x    = (const float*)d_in[0];
  const float* adj  = (const float*)d_in[1];
  const float* wini = (const float*)d_in[2];
  const float* hH   = (const float*)d_in[3];
  const float* ha   = (const float*)d_in[4];
  const float* oH   = (const float*)d_in[5];
  const float* oa   = (const float*)d_in[6];
  const float* l2w  = (const float*)d_in[7];

  char* ws = (char*)d_ws;
  size_t off = 0;
  auto alloc = [&](size_t bytes) -> void* {
    void* p = ws + off;
    off += (bytes + 4095) & ~(size_t)4095;
    return p;
  };
  unsigned short* htr4 = (unsigned short*)alloc((size_t)4 * 64 * Nn * 2);
  float* f14           = (float*)alloc((size_t)4 * Nn * 4);
  float* f24           = (float*)alloc((size_t)4 * Nn * 4);
  int* rank4           = (int*)alloc((size_t)4 * Nn * 4);
  int* mj4             = (int*)alloc((size_t)4 * Nn * 4);
  unsigned short* att4 = (unsigned short*)alloc((size_t)4 * Nn * Nn * 2);  // 128MB
  float* cpart4        = (float*)alloc((size_t)4 * 8 * Nn * 64 * 4);       // 32MB
  float* cat           = (float*)alloc((size_t)Nn * 256 * 4);              // 4MB
  float* x1            = (float*)alloc((size_t)Nn * 64 * 4);
  unsigned short* bth  = (unsigned short*)alloc((size_t)Nn * 64 * 2);
  unsigned short* btl  = (unsigned short*)alloc((size_t)Nn * 64 * 2);

  const size_t AS = (size_t)Nn * Nn;       // att stride (ushort)
  const size_t BS = (size_t)64 * Nn;       // htr stride (ushort)
  const size_t CS = (size_t)8 * Nn * 64;   // cpart stride (float)

  const float* prev = wini;
  int pdin = Nn;   // w_init is [N, 64] -> din for layer 1 is N? no: prev @ Hm, prev=[N,64]
  // NOTE: w_init shape is [N=4096, D1=64]; as "prev" it is an [N,64] feature
  // matrix, so din = 64 for cell 0 heads.
  pdin = 64;

  for (int cell = 0; cell < 2; ++cell) {
    const float* adj_c = adj + (size_t)cell * Nn * Nn;
    // 4 heads, batched
    k_hf4<<<dim3(Nn / 4, 4), 256, 0, stream>>>(
        prev, pdin, hH + (size_t)cell * 4 * 64 * 64, (size_t)64 * 64,
        ha + (size_t)cell * 4 * 128, (size_t)128, htr4, f14, f24);
    k_rank4<<<dim3(32, 4), 256, 0, stream>>>(f14, f24, rank4, mj4);
    k_rows4<<<dim3(Nn), 256, 0, stream>>>(adj_c, rank4, f14, f24, mj4, att4, 4);
    k_gemm<0, 64, false><<<dim3(64, 8, 4), 256, 0, stream>>>(
        att4, AS, htr4, nullptr, BS, cpart4, CS);
    k_red4<64><<<dim3(Nn * 64 / 256, 4), 256, 0, stream>>>(
        cpart4, CS, cat, 256, 0, 64, 1, nullptr, nullptr);
    // out-GAT
    k_hf4<<<dim3(Nn / 4, 1), 256, 0, stream>>>(
        cat, 256, oH + (size_t)cell * 256 * 64, 0,
        oa + (size_t)cell * 128, 0, htr4, f14, f24);
    k_rank4<<<dim3(32, 1), 256, 0, stream>>>(f14, f24, rank4, mj4);
    k_rows4<<<dim3(Nn), 256, 0, stream>>>(adj_c, rank4, f14, f24, mj4, att4, 1);
    k_gemm<0, 64, false><<<dim3(64, 8, 1), 256, 0, stream>>>(
        att4, 0, htr4, nullptr, 0, cpart4, 0);
    if (cell == 0)
      k_red4<64><<<dim3(Nn * 64 / 256, 1), 256, 0, stream>>>(
          cpart4, 0, x1, 64, 0, 0, 1, nullptr, nullptr);
    else
      k_red4<64><<<dim3(Nn * 64 / 256, 1), 256, 0, stream>>>(
          cpart4, 0, nullptr, 0, 0, 0, 1, bth, btl);
    prev = x1;
    pdin = 64;
  }

  // tail (cell 1 only; cell 0's h1/h2 are dead in the reference)
  const float* adj1 = adj + (size_t)Nn * Nn;
  const float* x1c  = x + (size_t)Nn * Nn;
  // t0 = x @ x1  (A f32 split, B = elu'd x1 split hi/lo)
  k_gemm<2, 64, true><<<dim3(64, 8, 1), 256, 0, stream>>>(
      x1c, 0, bth, btl, 0, cpart4, 0);
  k_red4<64><<<dim3(Nn * 64 / 256, 1), 256, 0, stream>>>(
      cpart4, 0, nullptr, 0, 0, 0, 0, bth, nullptr);       // t0 -> bth
  // h1 = relu(adj1 @ t0); u = h1 @ l2w  (fused)
  k_gemm<1, 64, false><<<dim3(64, 8, 1), 256, 0, stream>>>(
      adj1, 0, bth, nullptr, 0, cpart4, 0);
  k_redU<<<dim3(Nn * 64 / 256), 256, 0, stream>>>(
      cpart4, l2w + 64 * 32, bth);                          // u -> bth[32][N]
  // h2 = adj1 @ u
  k_gemm<1, 32, false><<<dim3(64, 8, 1), 256, 0, stream>>>(
      adj1, 0, bth, nullptr, 0, cpart4, 0);
  k_red4<32><<<dim3(Nn * 32 / 256, 1), 256, 0, stream>>>(
      cpart4, 0, (float*)d_out, 32, 0, 0, 0, nullptr, nullptr);
}

// Round 4
// 1329.738 us; speedup vs baseline: 1.0113x; 1.0113x over previous
//
#include <hip/hip_runtime.h>
#include <hip/hip_bf16.h>
#include <cstdint>
#include <cstddef>

constexpr int Nn = 4096;
constexpr int NB = 64;        // value buckets for leaky-relu threshold
constexpr int MC = 3 * NB;    // M columns per head: indicator | f1hi | f1lo

typedef __attribute__((ext_vector_type(8))) short bf16x8;
typedef __attribute__((ext_vector_type(8))) short short8;
typedef __attribute__((ext_vector_type(4))) float f32x4;

__device__ __forceinline__ unsigned short f2bf(float x) {
  union { float f; unsigned u; } v; v.f = x;
  unsigned r = v.u + 0x7FFFu + ((v.u >> 16) & 1u);
  return (unsigned short)(r >> 16);
}
__device__ __forceinline__ float bf2f(unsigned short b) {
  union { unsigned u; float f; } v; v.u = ((unsigned)b) << 16; return v.f;
}

// f32 -> bf16, 8 elems/thread
__global__ __launch_bounds__(256) void k_cvt(
    const float* __restrict__ in, unsigned short* __restrict__ out) {
  size_t id = ((size_t)blockIdx.x * 256 + threadIdx.x) * 8;
  const float4 a = *(const float4*)(in + id);
  const float4 b = *(const float4*)(in + id + 4);
  short8 v;
  v[0] = (short)f2bf(a.x); v[1] = (short)f2bf(a.y);
  v[2] = (short)f2bf(a.z); v[3] = (short)f2bf(a.w);
  v[4] = (short)f2bf(b.x); v[5] = (short)f2bf(b.y);
  v[6] = (short)f2bf(b.z); v[7] = (short)f2bf(b.w);
  *(short8*)(out + id) = v;
}

// h = prev[N,din] @ W[din,64]; writes htr (bf16 transposed [64][N]),
// f1 = h@av[:64], f2 = h@av[64:]. One wave per row, lane == out dim.
__global__ __launch_bounds__(256) void k_hf4(
    const float* __restrict__ prev, int din,
    const float* __restrict__ Wb, size_t wstride,
    const float* __restrict__ avb, size_t avstride,
    unsigned short* __restrict__ htrb,
    float* __restrict__ f1b, float* __restrict__ f2b) {
  __shared__ float Wl[64 * 64];
  int h = blockIdx.y;
  const float* W  = Wb + (size_t)h * wstride;
  const float* av = avb + (size_t)h * avstride;
  unsigned short* htr = htrb + (size_t)h * 64 * Nn;
  int t = threadIdx.x;
  int r = __builtin_amdgcn_readfirstlane(blockIdx.x * 4 + (t >> 6));
  int d = t & 63;
  const float* pr = prev + (size_t)r * din;
  float acc = 0.f;
  for (int kb = 0; kb < din; kb += 64) {
    for (int i = t; i < 64 * 64; i += 256) Wl[i] = W[kb * 64 + i];
    __syncthreads();
    #pragma unroll 8
    for (int k = 0; k < 64; ++k) acc = fmaf(pr[kb + k], Wl[k * 64 + d], acc);
    __syncthreads();
  }
  htr[(size_t)d * Nn + r] = f2bf(acc);
  float p1 = acc * av[d];
  float p2 = acc * av[64 + d];
  #pragma unroll
  for (int off = 32; off; off >>= 1) {
    p1 += __shfl_down(p1, off);
    p2 += __shfl_down(p2, off);
  }
  if (d == 0) { f1b[h * Nn + r] = p1; f2b[h * Nn + r] = p2; }
}

// Build M (bf16, [h][MC][Nn] col-major-over-k) densely + jb[j] thresholds.
// grid (MC, nh). Each block: stage f1 in LDS, redundant min/max, write one col.
__global__ __launch_bounds__(256) void k_mbuild(
    const float* __restrict__ f1b, const float* __restrict__ f2b,
    unsigned short* __restrict__ Mb, unsigned char* __restrict__ jbb) {
  __shared__ float fl[Nn];
  __shared__ float red[16];
  int h = blockIdx.y, col = blockIdx.x;
  const float* f1 = f1b + (size_t)h * Nn;
  int t = threadIdx.x, lane = t & 63, wv = t >> 6;
  float lmin = 3e38f, lmax = -3e38f;
  #pragma unroll
  for (int i = 0; i < 16; ++i) {
    float v = f1[i * 256 + t];
    fl[i * 256 + t] = v;
    lmin = fminf(lmin, v); lmax = fmaxf(lmax, v);
  }
  #pragma unroll
  for (int off = 32; off; off >>= 1) {
    lmin = fminf(lmin, __shfl_xor(lmin, off));
    lmax = fmaxf(lmax, __shfl_xor(lmax, off));
  }
  if (lane == 0) { red[wv] = lmin; red[8 + wv] = lmax; }
  __syncthreads();
  float emin = fminf(fminf(red[0], red[1]), fminf(red[2], red[3]));
  float emax = fmaxf(fmaxf(red[8], red[9]), fmaxf(red[10], red[11]));
  float wr = emax - emin;
  float invw = (wr > 0.f) ? (float)NB / wr : 0.f;
  int part = col >> 6, bb = col & 63;
  unsigned short* mrow = Mb + ((size_t)h * MC + col) * Nn;
  #pragma unroll
  for (int i = 0; i < 16; ++i) {
    int k = i * 256 + t;
    float f = fl[k];
    int b = (int)floorf((emax - f) * invw);
    b = b < 0 ? 0 : (b > NB - 1 ? NB - 1 : b);
    unsigned short val = 0;
    if (b == bb) {
      if (part == 0) val = 0x3F80;   // bf16(1.0)
      else {
        unsigned short hb = f2bf(f);
        val = (part == 1) ? hb : f2bf(f - bf2f(hb));
      }
    }
    mrow[k] = val;
  }
  if (col == 0) {
    const float* f2 = f2b + (size_t)h * Nn;
    #pragma unroll
    for (int i = 0; i < 16; ++i) {
      int j = i * 256 + t;
      int b = (int)floorf((emax + f2[j]) * invw + 0.5f);
      b = b < 0 ? 0 : (b > NB ? NB : b);
      jbb[(size_t)h * Nn + j] = (unsigned char)b;
    }
  }
}

// C[4096,NC] = A[4096,4096] @ B ; B transposed bf16 [NC][4096].
// AMODE 0: A bf16; 2: A f32 split hi/lo (3-MFMA). Split-K via gridDim.y
// into Cpart[kc][4096][NC]; batched over blockIdx.z (h).
template<int AMODE, int NC, bool BSPLIT>
__global__ __launch_bounds__(256) void k_gemm(
    const void* __restrict__ Ap, size_t astride,
    const unsigned short* __restrict__ Bthb,
    const unsigned short* __restrict__ Btlb, size_t bstride,
    float* __restrict__ Cpartb, size_t cstride) {
  constexpr int NT = NC / 16;
  int h = blockIdx.z;
  const unsigned short* Bth = Bthb + (size_t)h * bstride;
  const unsigned short* Btl = Btlb ? Btlb + (size_t)h * bstride : nullptr;
  float* Cpart = Cpartb + (size_t)h * cstride;
  int t = threadIdx.x;
  int wv = t >> 6, l = t & 63;
  int l15 = l & 15, lq = l >> 4;
  int row0 = blockIdx.x * 64 + wv * 16;
  int kc = blockIdx.y;
  int kslice = Nn / gridDim.y;
  f32x4 acc[NT];
  #pragma unroll
  for (int i = 0; i < NT; ++i) acc[i] = (f32x4){0.f, 0.f, 0.f, 0.f};
  int row = row0 + l15;
  int kb = kc * kslice + lq * 8;
  for (int k0 = 0; k0 < kslice; k0 += 32) {
    int k = kb + k0;
    bf16x8 af, af2;
    if constexpr (AMODE == 0) {
      af = *(const bf16x8*)((const unsigned short*)Ap + (size_t)h * astride +
                            (size_t)row * Nn + k);
    } else {
      const float* fp = (const float*)Ap + (size_t)row * Nn + k;
      const float4 xa = *(const float4*)fp;
      const float4 xb = *(const float4*)(fp + 4);
      float xs[8] = {xa.x, xa.y, xa.z, xa.w, xb.x, xb.y, xb.z, xb.w};
      #pragma unroll
      for (int i = 0; i < 8; ++i) {
        unsigned short hb = f2bf(xs[i]);
        ((unsigned short*)&af)[i] = hb;
        if constexpr (AMODE == 2)
          ((unsigned short*)&af2)[i] = f2bf(xs[i] - bf2f(hb));
      }
    }
    #pragma unroll
    for (int ct = 0; ct < NT; ++ct) {
      bf16x8 bh = *(const bf16x8*)(Bth + (size_t)(ct * 16 + l15) * Nn + k);
      acc[ct] = __builtin_amdgcn_mfma_f32_16x16x32_bf16(af, bh, acc[ct], 0, 0, 0);
      if constexpr (BSPLIT) {
        bf16x8 bl = *(const bf16x8*)(Btl + (size_t)(ct * 16 + l15) * Nn + k);
        acc[ct] = __builtin_amdgcn_mfma_f32_16x16x32_bf16(af, bl, acc[ct], 0, 0, 0);
      }
      if constexpr (AMODE == 2)
        acc[ct] = __builtin_amdgcn_mfma_f32_16x16x32_bf16(af2, bh, acc[ct], 0, 0, 0);
    }
  }
  // D layout (m89-verified): col = lane&15, row = 4*(lane>>4)+reg
  #pragma unroll
  for (int ct = 0; ct < NT; ++ct) {
    #pragma unroll
    for (int q = 0; q < 4; ++q) {
      int rr = row0 + lq * 4 + q;
      int cc = ct * 16 + l15;
      Cpart[((size_t)kc * Nn + rr) * NC + cc] = acc[ct][q];
    }
  }
}

// Per row r, per head: sum SK hist parts, 64-bucket prefix scan, evaluate
// s[r,j] via bucket lookup, row softmax, write bf16 att row.
template<int SK>
__global__ __launch_bounds__(256) void k_sm(
    const float* __restrict__ Hb, const float* __restrict__ f2b,
    const unsigned char* __restrict__ jbb, unsigned short* __restrict__ attb,
    int nh) {
  __shared__ float hr[MC];
  __shared__ float C0x[NB + 1], C1x[NB + 1];
  __shared__ float red[8];
  int t = threadIdx.x;
  int lane = t & 63, wv = t >> 6;
  int r = blockIdx.x;
  for (int h = 0; h < nh; ++h) {
    if (h) __syncthreads();
    if (t < MC) {
      const float* p = Hb + (size_t)h * SK * Nn * MC + (size_t)r * MC + t;
      float s = 0.f;
      #pragma unroll
      for (int sk = 0; sk < SK; ++sk) s += p[(size_t)sk * Nn * MC];
      hr[t] = s;
    }
    __syncthreads();
    if (t < 64) {
      float v0 = hr[t];
      float v1 = hr[64 + t] + hr[128 + t];
      #pragma unroll
      for (int off = 1; off < 64; off <<= 1) {
        float u0 = __shfl_up(v0, off);
        float u1 = __shfl_up(v1, off);
        if (lane >= off) { v0 += u0; v1 += u1; }
      }
      C0x[t + 1] = v0; C1x[t + 1] = v1;
      if (t == 0) { C0x[0] = 0.f; C1x[0] = 0.f; }
    }
    __syncthreads();
    float S0 = C0x[NB], S1 = C1x[NB];
    const float* f2 = f2b + (size_t)h * Nn;
    const unsigned char* jb = jbb + (size_t)h * Nn;
    float sv[16];
    float mx = -3.0e38f;
    #pragma unroll
    for (int c = 0; c < 16; ++c) {
      int j = c * 256 + t;
      float fj = f2[j];
      int b = jb[j];
      float s = 0.2f * fmaf(fj, S0, S1) + 0.8f * fmaf(fj, C0x[b], C1x[b]);
      sv[c] = s;
      mx = fmaxf(mx, s);
    }
    #pragma unroll
    for (int off = 32; off; off >>= 1) mx = fmaxf(mx, __shfl_xor(mx, off));
    __syncthreads();
    if (lane == 0) red[wv] = mx;
    __syncthreads();
    mx = fmaxf(fmaxf(red[0], red[1]), fmaxf(red[2], red[3]));
    float pv[16];
    float sum = 0.f;
    #pragma unroll
    for (int c = 0; c < 16; ++c) { float p = __expf(sv[c] - mx); pv[c] = p; sum += p; }
    #pragma unroll
    for (int off = 32; off; off >>= 1) sum += __shfl_xor(sum, off);
    __syncthreads();
    if (lane == 0) red[4 + wv] = sum;
    __syncthreads();
    float inv = 1.f / (red[4] + red[5] + red[6] + red[7]);
    unsigned short* orow = attb + (size_t)h * Nn * Nn + (size_t)r * Nn;
    #pragma unroll
    for (int c = 0; c < 16; ++c) orow[c * 256 + t] = f2bf(pv[c] * inv);
  }
}

// sum split-K partials + epilogue (0 none, 1 elu, 2 relu); optional strided
// f32 write and/or transposed bf16 hi/lo planes. Batched over blockIdx.y.
template<int NC, int SK>
__global__ __launch_bounds__(256) void k_red4(
    const float* __restrict__ Cpartb, size_t cph,
    float* __restrict__ dst, int ldd, int coff0, int coffstep, int epi,
    unsigned short* __restrict__ oh, unsigned short* __restrict__ ol) {
  int h = blockIdx.y;
  const float* cp = Cpartb + (size_t)h * cph;
  int id = blockIdx.x * 256 + threadIdx.x;
  int r = id / NC, c = id % NC;
  float s = 0.f;
  #pragma unroll
  for (int kc = 0; kc < SK; ++kc) s += cp[((size_t)kc * Nn + r) * NC + c];
  if (epi == 1) s = (s > 0.f) ? s : expm1f(s);
  else if (epi == 2) s = fmaxf(s, 0.f);
  if (dst) dst[(size_t)r * ldd + coff0 + h * coffstep + c] = s;
  if (oh) {
    unsigned short hb = f2bf(s);
    oh[(size_t)c * Nn + r] = hb;
    if (ol) ol[(size_t)c * Nn + r] = f2bf(s - bf2f(hb));
  }
}

// fused: h1 = relu(sum partials); u = h1 @ l2w[64,32]; write ut bf16 [32][N]
__global__ __launch_bounds__(256) void k_redU(
    const float* __restrict__ Cpart, const float* __restrict__ W,
    unsigned short* __restrict__ ut) {
  __shared__ float hl[4][64];
  __shared__ float Wl[64 * 32];
  int t = threadIdx.x;
  for (int i = t; i < 64 * 32; i += 256) Wl[i] = W[i];
  int id = blockIdx.x * 256 + t;     // grid.x = 1024 -> 4 rows/block
  int r = id >> 6, c = id & 63;
  float s = 0.f;
  #pragma unroll
  for (int kc = 0; kc < 4; ++kc) s += Cpart[((size_t)kc * Nn + r) * 64 + c];
  hl[t >> 6][c] = fmaxf(s, 0.f);
  __syncthreads();
  if (t < 128) {
    int lr = t >> 5, d = t & 31;
    int row = blockIdx.x * 4 + lr;
    const float* hrr = hl[lr];
    float acc = 0.f;
    #pragma unroll 8
    for (int k = 0; k < 64; ++k) acc = fmaf(hrr[k], Wl[k * 32 + d], acc);
    ut[(size_t)d * Nn + row] = f2bf(acc);
  }
}

extern "C" void kernel_launch(void* const* d_in, const int* in_sizes, int n_in,
                              void* d_out, int out_size, void* d_ws, size_t ws_size,
                              hipStream_t stream) {
  (void)in_sizes; (void)n_in; (void)out_size; (void)ws_size;
  const float* x    = (const float*)d_in[0];
  const float* adj  = (const float*)d_in[1];
  const float* wini = (const float*)d_in[2];
  const float* hH   = (const float*)d_in[3];
  const float* ha   = (const float*)d_in[4];
  const float* oH   = (const float*)d_in[5];
  const float* oa   = (const float*)d_in[6];
  const float* l2w  = (const float*)d_in[7];

  char* ws = (char*)d_ws;
  size_t off = 0;
  auto alloc = [&](size_t bytes) -> void* {
    void* p = ws + off;
    off += (bytes + 4095) & ~(size_t)4095;
    return p;
  };
  unsigned short* adjbf = (unsigned short*)alloc((size_t)Nn * Nn * 2);        // 32MB
  unsigned short* htr4  = (unsigned short*)alloc((size_t)4 * 64 * Nn * 2);    // 2MB
  float* f14            = (float*)alloc((size_t)4 * Nn * 4);
  float* f24            = (float*)alloc((size_t)4 * Nn * 4);
  unsigned char* jb4    = (unsigned char*)alloc((size_t)4 * Nn);
  unsigned short* Mbuf  = (unsigned short*)alloc((size_t)4 * MC * Nn * 2);    // 6MB
  float* Hbuf           = (float*)alloc((size_t)4 * 4 * Nn * MC * 4);         // 48MB
  unsigned short* att4  = (unsigned short*)alloc((size_t)4 * Nn * Nn * 2);    // 128MB
  float* cpart          = (float*)alloc((size_t)4 * 4 * Nn * 64 * 4);         // 16MB
  float* cat            = (float*)alloc((size_t)Nn * 256 * 4);                // 4MB
  float* x1             = (float*)alloc((size_t)Nn * 64 * 4);
  unsigned short* bth   = (unsigned short*)alloc((size_t)Nn * 64 * 2);
  unsigned short* btl   = (unsigned short*)alloc((size_t)Nn * 64 * 2);

  const size_t AS  = (size_t)Nn * Nn;        // att stride per head (ushort)
  const size_t BS  = (size_t)64 * Nn;        // htr stride per head (ushort)
  const size_t MS  = (size_t)MC * Nn;        // M stride per head (ushort)
  const size_t HS  = (size_t)4 * Nn * MC;    // Hbuf stride per head (f32, SK=4)
  const size_t CS  = (size_t)4 * Nn * 64;    // cpart stride per head (f32, SK=4)

  // stage = one GAT pass (nh heads sharing adj_c, input xin[*,din])
  auto run_stage = [&](const float* xin, int din, const float* Hm, size_t hms,
                       const float* av, size_t avs, int nh) {
    k_hf4<<<dim3(Nn / 4, nh), 256, 0, stream>>>(xin, din, Hm, hms, av, avs,
                                                htr4, f14, f24);
    k_mbuild<<<dim3(MC, nh), 256, 0, stream>>>(f14, f24, Mbuf, jb4);
    k_gemm<0, MC, false><<<dim3(64, 4, nh), 256, 0, stream>>>(
        adjbf, 0, Mbuf, nullptr, MS, Hbuf, HS);
    k_sm<4><<<dim3(Nn), 256, 0, stream>>>(Hbuf, f24, jb4, att4, nh);
    k_gemm<0, 64, false><<<dim3(64, 4, nh), 256, 0, stream>>>(
        att4, AS, htr4, nullptr, BS, cpart, CS);
  };

  const float* prev = wini;
  for (int cell = 0; cell < 2; ++cell) {
    const float* adj_c = adj + (size_t)cell * Nn * Nn;
    k_cvt<<<dim3(Nn * Nn / 8 / 256), 256, 0, stream>>>(adj_c, adjbf);
    // 4 heads
    run_stage(prev, 64, hH + (size_t)cell * 4 * 64 * 64, (size_t)64 * 64,
              ha + (size_t)cell * 4 * 128, 128, 4);
    k_red4<64, 4><<<dim3(Nn * 64 / 256, 4), 256, 0, stream>>>(
        cpart, CS, cat, 256, 0, 64, 1, nullptr, nullptr);
    // out-GAT
    run_stage(cat, 256, oH + (size_t)cell * 256 * 64, 0,
              oa + (size_t)cell * 128, 0, 1);
    if (cell == 0)
      k_red4<64, 4><<<dim3(Nn * 64 / 256, 1), 256, 0, stream>>>(
          cpart, 0, x1, 64, 0, 0, 1, nullptr, nullptr);
    else
      k_red4<64, 4><<<dim3(Nn * 64 / 256, 1), 256, 0, stream>>>(
          cpart, 0, nullptr, 0, 0, 0, 1, bth, btl);
    prev = x1;
  }

  // tail (cell 1 only; adjbf currently holds cell-1 adj in bf16)
  const float* x1c = x + (size_t)Nn * Nn;
  // t0 = x @ elu(x1)  (A f32 split hi/lo, B planes)
  k_gemm<2, 64, true><<<dim3(64, 4, 1), 256, 0, stream>>>(
      x1c, 0, bth, btl, 0, cpart, 0);
  k_red4<64, 4><<<dim3(Nn * 64 / 256, 1), 256, 0, stream>>>(
      cpart, 0, nullptr, 0, 0, 0, 0, bth, nullptr);        // t0 -> bth
  // h1 = relu(adj1 @ t0); u = h1 @ l2w  (fused into k_redU)
  k_gemm<0, 64, false><<<dim3(64, 4, 1), 256, 0, stream>>>(
      adjbf, 0, bth, nullptr, 0, cpart, 0);
  k_redU<<<dim3(Nn * 64 / 256), 256, 0, stream>>>(
      cpart, l2w + 64 * 32, bth);                          // u -> bth[32][N]
  // h2 = adj1 @ u
  k_gemm<0, 32, false><<<dim3(64, 4, 1), 256, 0, stream>>>(
      adjbf, 0, bth, nullptr, 0, cpart, 0);
  k_red4<32, 4><<<dim3(Nn * 32 / 256, 1), 256, 0, stream>>>(
      cpart, 0, (float*)d_out, 32, 0, 0, 0, nullptr, nullptr);
}

// Round 5
// 762.104 us; speedup vs baseline: 1.7645x; 1.7448x over previous
//
#include <hip/hip_runtime.h>
#include <hip/hip_bf16.h>
#include <cstdint>
#include <cstddef>

constexpr int Nn = 4096;
constexpr int NB = 64;        // value buckets for leaky-relu threshold
constexpr int MC = 3 * NB;    // M columns per head: indicator | f1hi | f1lo

typedef __attribute__((ext_vector_type(8))) short bf16x8;
typedef __attribute__((ext_vector_type(8))) short short8;
typedef __attribute__((ext_vector_type(4))) float f32x4;

__device__ __forceinline__ unsigned short f2bf(float x) {
  union { float f; unsigned u; } v; v.f = x;
  unsigned r = v.u + 0x7FFFu + ((v.u >> 16) & 1u);
  return (unsigned short)(r >> 16);
}
__device__ __forceinline__ float bf2f(unsigned short b) {
  union { unsigned u; float f; } v; v.u = ((unsigned)b) << 16; return v.f;
}

// f32 -> bf16, 8 elems/thread
__global__ __launch_bounds__(256) void k_cvt(
    const float* __restrict__ in, unsigned short* __restrict__ out) {
  size_t id = ((size_t)blockIdx.x * 256 + threadIdx.x) * 8;
  const float4 a = *(const float4*)(in + id);
  const float4 b = *(const float4*)(in + id + 4);
  short8 v;
  v[0] = (short)f2bf(a.x); v[1] = (short)f2bf(a.y);
  v[2] = (short)f2bf(a.z); v[3] = (short)f2bf(a.w);
  v[4] = (short)f2bf(b.x); v[5] = (short)f2bf(b.y);
  v[6] = (short)f2bf(b.z); v[7] = (short)f2bf(b.w);
  *(short8*)(out + id) = v;
}

// h = prev[N,din] @ W[din,64]; writes htr (bf16 transposed [64][N]),
// f1 = h@av[:64], f2 = h@av[64:]. One wave per row, lane == out dim.
__global__ __launch_bounds__(256) void k_hf4(
    const float* __restrict__ prev, int din,
    const float* __restrict__ Wb, size_t wstride,
    const float* __restrict__ avb, size_t avstride,
    unsigned short* __restrict__ htrb,
    float* __restrict__ f1b, float* __restrict__ f2b) {
  __shared__ float Wl[64 * 64];
  int h = blockIdx.y;
  const float* W  = Wb + (size_t)h * wstride;
  const float* av = avb + (size_t)h * avstride;
  unsigned short* htr = htrb + (size_t)h * 64 * Nn;
  int t = threadIdx.x;
  int r = __builtin_amdgcn_readfirstlane(blockIdx.x * 4 + (t >> 6));
  int d = t & 63;
  const float* pr = prev + (size_t)r * din;
  float acc = 0.f;
  for (int kb = 0; kb < din; kb += 64) {
    for (int i = t; i < 64 * 64; i += 256) Wl[i] = W[kb * 64 + i];
    __syncthreads();
    #pragma unroll 8
    for (int k = 0; k < 64; ++k) acc = fmaf(pr[kb + k], Wl[k * 64 + d], acc);
    __syncthreads();
  }
  htr[(size_t)d * Nn + r] = f2bf(acc);
  float p1 = acc * av[d];
  float p2 = acc * av[64 + d];
  #pragma unroll
  for (int off = 32; off; off >>= 1) {
    p1 += __shfl_down(p1, off);
    p2 += __shfl_down(p2, off);
  }
  if (d == 0) { f1b[h * Nn + r] = p1; f2b[h * Nn + r] = p2; }
}

// Build M (bf16, [h][MC][Nn]) densely + jb[j] thresholds. grid (MC, nh).
__global__ __launch_bounds__(256) void k_mbuild(
    const float* __restrict__ f1b, const float* __restrict__ f2b,
    unsigned short* __restrict__ Mb, unsigned char* __restrict__ jbb) {
  __shared__ float fl[Nn];
  __shared__ float red[16];
  int h = blockIdx.y, col = blockIdx.x;
  const float* f1 = f1b + (size_t)h * Nn;
  int t = threadIdx.x, lane = t & 63, wv = t >> 6;
  float lmin = 3e38f, lmax = -3e38f;
  #pragma unroll
  for (int i = 0; i < 16; ++i) {
    float v = f1[i * 256 + t];
    fl[i * 256 + t] = v;
    lmin = fminf(lmin, v); lmax = fmaxf(lmax, v);
  }
  #pragma unroll
  for (int off = 32; off; off >>= 1) {
    lmin = fminf(lmin, __shfl_xor(lmin, off));
    lmax = fmaxf(lmax, __shfl_xor(lmax, off));
  }
  if (lane == 0) { red[wv] = lmin; red[8 + wv] = lmax; }
  __syncthreads();
  float emin = fminf(fminf(red[0], red[1]), fminf(red[2], red[3]));
  float emax = fmaxf(fmaxf(red[8], red[9]), fmaxf(red[10], red[11]));
  float wr = emax - emin;
  float invw = (wr > 0.f) ? (float)NB / wr : 0.f;
  int part = col >> 6, bb = col & 63;
  unsigned short* mrow = Mb + ((size_t)h * MC + col) * Nn;
  #pragma unroll
  for (int i = 0; i < 16; ++i) {
    int k = i * 256 + t;
    float f = fl[k];
    int b = (int)floorf((emax - f) * invw);
    b = b < 0 ? 0 : (b > NB - 1 ? NB - 1 : b);
    unsigned short val = 0;
    if (b == bb) {
      if (part == 0) val = 0x3F80;   // bf16(1.0)
      else {
        unsigned short hb = f2bf(f);
        val = (part == 1) ? hb : f2bf(f - bf2f(hb));
      }
    }
    mrow[k] = val;
  }
  if (col == 0) {
    const float* f2 = f2b + (size_t)h * Nn;
    #pragma unroll
    for (int i = 0; i < 16; ++i) {
      int j = i * 256 + t;
      int b = (int)floorf((emax + f2[j]) * invw + 0.5f);
      b = b < 0 ? 0 : (b > NB ? NB : b);
      jbb[(size_t)h * Nn + j] = (unsigned char)b;
    }
  }
}

// LDS-staged tile GEMM. C[4096, ldc-wide] += A[4096,4096] @ B^T-slice.
// AMODE 0: A bf16; 2: A f32 split hi/lo (extra LDS plane, 2 MFMA per frag).
// BSPLIT: B hi/lo planes. Tile BM=128 x NCB, BK=64, 4 waves (32 rows each).
// grid (Nn/128, SK*CG, nh): cg = col-group (reads B rows cg*NCB..), kc = K-chunk.
// Cpart layout per head: [SK][Nn][ldc], col offset cg*NCB.
template<int AMODE, int NCB, bool BSPLIT>
__global__ __launch_bounds__(256) void k_gemm(
    const void* __restrict__ Ap, size_t astride,
    const unsigned short* __restrict__ Bthb,
    const unsigned short* __restrict__ Btlb, size_t bstride,
    float* __restrict__ Cpartb, size_t cstride, int ldc, int CG) {
  constexpr int APL = (AMODE == 2) ? 2 : 1;
  constexpr int BPL = BSPLIT ? 2 : 1;
  constexpr int NT = NCB / 16;
  __shared__ __align__(16) unsigned short Abuf[APL][128][72];
  __shared__ __align__(16) unsigned short Bbuf[BPL][NCB][72];
  int h = blockIdx.z;
  int cg = blockIdx.y % CG;
  int kc = blockIdx.y / CG;
  int SK = gridDim.y / CG;
  int kslice = Nn / SK;
  const unsigned short* Bth = Bthb + (size_t)h * bstride + (size_t)(cg * NCB) * Nn;
  const unsigned short* Btl = BSPLIT
      ? (Btlb + (size_t)h * bstride + (size_t)(cg * NCB) * Nn) : nullptr;
  float* Cpart = Cpartb + (size_t)h * cstride + (size_t)kc * Nn * ldc + cg * NCB;
  int t = threadIdx.x;
  int wv = t >> 6, l = t & 63;
  int l15 = l & 15, lq = l >> 4;
  int row0 = blockIdx.x * 128;
  f32x4 acc[2][NT] = {};
  for (int kt = kc * kslice; kt < (kc + 1) * kslice; kt += 64) {
    __syncthreads();
    // stage A: 128 rows x 8 chunks(16B), 4 chunks/thread
    #pragma unroll
    for (int i = 0; i < 4; ++i) {
      int cid = i * 256 + t;
      int row = cid >> 3, ch = cid & 7;
      if constexpr (AMODE == 0) {
        bf16x8 v = *(const bf16x8*)((const unsigned short*)Ap +
                     (size_t)h * astride + (size_t)(row0 + row) * Nn + kt + ch * 8);
        *(bf16x8*)&Abuf[0][row][ch * 8] = v;
      } else {
        const float* fp = (const float*)Ap + (size_t)(row0 + row) * Nn + kt + ch * 8;
        const float4 xa = *(const float4*)fp;
        const float4 xb = *(const float4*)(fp + 4);
        float xs[8] = {xa.x, xa.y, xa.z, xa.w, xb.x, xb.y, xb.z, xb.w};
        bf16x8 hi, lo;
        #pragma unroll
        for (int e = 0; e < 8; ++e) {
          unsigned short hb = f2bf(xs[e]);
          hi[e] = (short)hb;
          lo[e] = (short)f2bf(xs[e] - bf2f(hb));
        }
        *(bf16x8*)&Abuf[0][row][ch * 8] = hi;
        *(bf16x8*)&Abuf[APL - 1][row][ch * 8] = lo;
      }
    }
    // stage B: NCB rows x 8 chunks, NCB/32 chunks/thread
    #pragma unroll
    for (int i = 0; i < NCB / 32; ++i) {
      int cid = i * 256 + t;
      int row = cid >> 3, ch = cid & 7;
      bf16x8 v = *(const bf16x8*)(Bth + (size_t)row * Nn + kt + ch * 8);
      *(bf16x8*)&Bbuf[0][row][ch * 8] = v;
      if constexpr (BSPLIT) {
        bf16x8 w = *(const bf16x8*)(Btl + (size_t)row * Nn + kt + ch * 8);
        *(bf16x8*)&Bbuf[BPL - 1][row][ch * 8] = w;
      }
    }
    __syncthreads();
    #pragma unroll
    for (int k0 = 0; k0 < 64; k0 += 32) {
      bf16x8 a0 = *(const bf16x8*)&Abuf[0][wv * 32 + l15][k0 + lq * 8];
      bf16x8 a1 = *(const bf16x8*)&Abuf[0][wv * 32 + 16 + l15][k0 + lq * 8];
      bf16x8 a0l, a1l;
      if constexpr (AMODE == 2) {
        a0l = *(const bf16x8*)&Abuf[APL - 1][wv * 32 + l15][k0 + lq * 8];
        a1l = *(const bf16x8*)&Abuf[APL - 1][wv * 32 + 16 + l15][k0 + lq * 8];
      }
      #pragma unroll
      for (int ct = 0; ct < NT; ++ct) {
        bf16x8 bh = *(const bf16x8*)&Bbuf[0][ct * 16 + l15][k0 + lq * 8];
        acc[0][ct] = __builtin_amdgcn_mfma_f32_16x16x32_bf16(a0, bh, acc[0][ct], 0, 0, 0);
        acc[1][ct] = __builtin_amdgcn_mfma_f32_16x16x32_bf16(a1, bh, acc[1][ct], 0, 0, 0);
        if constexpr (BSPLIT) {
          bf16x8 bl = *(const bf16x8*)&Bbuf[BPL - 1][ct * 16 + l15][k0 + lq * 8];
          acc[0][ct] = __builtin_amdgcn_mfma_f32_16x16x32_bf16(a0, bl, acc[0][ct], 0, 0, 0);
          acc[1][ct] = __builtin_amdgcn_mfma_f32_16x16x32_bf16(a1, bl, acc[1][ct], 0, 0, 0);
        }
        if constexpr (AMODE == 2) {
          acc[0][ct] = __builtin_amdgcn_mfma_f32_16x16x32_bf16(a0l, bh, acc[0][ct], 0, 0, 0);
          acc[1][ct] = __builtin_amdgcn_mfma_f32_16x16x32_bf16(a1l, bh, acc[1][ct], 0, 0, 0);
        }
      }
    }
  }
  // D layout (m89-verified): col = lane&15, row = 4*(lane>>4)+reg
  #pragma unroll
  for (int mi = 0; mi < 2; ++mi) {
    #pragma unroll
    for (int ct = 0; ct < NT; ++ct) {
      #pragma unroll
      for (int q = 0; q < 4; ++q) {
        int r = row0 + wv * 32 + mi * 16 + lq * 4 + q;
        Cpart[(size_t)r * ldc + ct * 16 + l15] = acc[mi][ct][q];
      }
    }
  }
}

// Per row r, per head: sum SK hist parts, 64-bucket prefix scan, evaluate
// s[r,j] via bucket lookup, row softmax, write bf16 att row.
template<int SK>
__global__ __launch_bounds__(256) void k_sm(
    const float* __restrict__ Hb, const float* __restrict__ f2b,
    const unsigned char* __restrict__ jbb, unsigned short* __restrict__ attb,
    int nh) {
  __shared__ float hr[MC];
  __shared__ float C0x[NB + 1], C1x[NB + 1];
  __shared__ float red[8];
  int t = threadIdx.x;
  int lane = t & 63, wv = t >> 6;
  int r = blockIdx.x;
  for (int h = 0; h < nh; ++h) {
    if (h) __syncthreads();
    if (t < MC) {
      const float* p = Hb + (size_t)h * SK * Nn * MC + (size_t)r * MC + t;
      float s = 0.f;
      #pragma unroll
      for (int sk = 0; sk < SK; ++sk) s += p[(size_t)sk * Nn * MC];
      hr[t] = s;
    }
    __syncthreads();
    if (t < 64) {
      float v0 = hr[t];
      float v1 = hr[64 + t] + hr[128 + t];
      #pragma unroll
      for (int off = 1; off < 64; off <<= 1) {
        float u0 = __shfl_up(v0, off);
        float u1 = __shfl_up(v1, off);
        if (lane >= off) { v0 += u0; v1 += u1; }
      }
      C0x[t + 1] = v0; C1x[t + 1] = v1;
      if (t == 0) { C0x[0] = 0.f; C1x[0] = 0.f; }
    }
    __syncthreads();
    float S0 = C0x[NB], S1 = C1x[NB];
    const float* f2 = f2b + (size_t)h * Nn;
    const unsigned char* jb = jbb + (size_t)h * Nn;
    float sv[16];
    float mx = -3.0e38f;
    #pragma unroll
    for (int c = 0; c < 16; ++c) {
      int j = c * 256 + t;
      float fj = f2[j];
      int b = jb[j];
      float s = 0.2f * fmaf(fj, S0, S1) + 0.8f * fmaf(fj, C0x[b], C1x[b]);
      sv[c] = s;
      mx = fmaxf(mx, s);
    }
    #pragma unroll
    for (int off = 32; off; off >>= 1) mx = fmaxf(mx, __shfl_xor(mx, off));
    __syncthreads();
    if (lane == 0) red[wv] = mx;
    __syncthreads();
    mx = fmaxf(fmaxf(red[0], red[1]), fmaxf(red[2], red[3]));
    float pv[16];
    float sum = 0.f;
    #pragma unroll
    for (int c = 0; c < 16; ++c) { float p = __expf(sv[c] - mx); pv[c] = p; sum += p; }
    #pragma unroll
    for (int off = 32; off; off >>= 1) sum += __shfl_xor(sum, off);
    __syncthreads();
    if (lane == 0) red[4 + wv] = sum;
    __syncthreads();
    float inv = 1.f / (red[4] + red[5] + red[6] + red[7]);
    unsigned short* orow = attb + (size_t)h * Nn * Nn + (size_t)r * Nn;
    #pragma unroll
    for (int c = 0; c < 16; ++c) orow[c * 256 + t] = f2bf(pv[c] * inv);
  }
}

// sum split-K partials + epilogue (0 none, 1 elu, 2 relu); optional strided
// f32 write and/or transposed bf16 hi/lo planes. Batched over blockIdx.y.
template<int NC, int SK>
__global__ __launch_bounds__(256) void k_red4(
    const float* __restrict__ Cpartb, size_t cph,
    float* __restrict__ dst, int ldd, int coff0, int coffstep, int epi,
    unsigned short* __restrict__ oh, unsigned short* __restrict__ ol) {
  int h = blockIdx.y;
  const float* cp = Cpartb + (size_t)h * cph;
  int id = blockIdx.x * 256 + threadIdx.x;
  int r = id / NC, c = id % NC;
  float s = 0.f;
  #pragma unroll
  for (int kc = 0; kc < SK; ++kc) s += cp[((size_t)kc * Nn + r) * NC + c];
  if (epi == 1) s = (s > 0.f) ? s : expm1f(s);
  else if (epi == 2) s = fmaxf(s, 0.f);
  if (dst) dst[(size_t)r * ldd + coff0 + h * coffstep + c] = s;
  if (oh) {
    unsigned short hb = f2bf(s);
    oh[(size_t)c * Nn + r] = hb;
    if (ol) ol[(size_t)c * Nn + r] = f2bf(s - bf2f(hb));
  }
}

// fused: h1 = relu(sum of 32 partials); u = h1 @ l2w[64,32]; ut bf16 [32][N]
__global__ __launch_bounds__(256) void k_redU(
    const float* __restrict__ Cpart, const float* __restrict__ W,
    unsigned short* __restrict__ ut) {
  __shared__ float hl[4][64];
  __shared__ float Wl[64 * 32];
  int t = threadIdx.x;
  for (int i = t; i < 64 * 32; i += 256) Wl[i] = W[i];
  int id = blockIdx.x * 256 + t;     // grid.x = 1024 -> 4 rows/block
  int r = id >> 6, c = id & 63;
  float s = 0.f;
  #pragma unroll
  for (int kc = 0; kc < 32; ++kc) s += Cpart[((size_t)kc * Nn + r) * 64 + c];
  hl[t >> 6][c] = fmaxf(s, 0.f);
  __syncthreads();
  if (t < 128) {
    int lr = t >> 5, d = t & 31;
    int row = blockIdx.x * 4 + lr;
    const float* hrr = hl[lr];
    float acc = 0.f;
    #pragma unroll 8
    for (int k = 0; k < 64; ++k) acc = fmaf(hrr[k], Wl[k * 32 + d], acc);
    ut[(size_t)d * Nn + row] = f2bf(acc);
  }
}

extern "C" void kernel_launch(void* const* d_in, const int* in_sizes, int n_in,
                              void* d_out, int out_size, void* d_ws, size_t ws_size,
                              hipStream_t stream) {
  (void)in_sizes; (void)n_in; (void)out_size; (void)ws_size;
  const float* x    = (const float*)d_in[0];
  const float* adj  = (const float*)d_in[1];
  const float* wini = (const float*)d_in[2];
  const float* hH   = (const float*)d_in[3];
  const float* ha   = (const float*)d_in[4];
  const float* oH   = (const float*)d_in[5];
  const float* oa   = (const float*)d_in[6];
  const float* l2w  = (const float*)d_in[7];

  char* ws = (char*)d_ws;
  size_t off = 0;
  auto alloc = [&](size_t bytes) -> void* {
    void* p = ws + off;
    off += (bytes + 4095) & ~(size_t)4095;
    return p;
  };
  unsigned short* adjbf = (unsigned short*)alloc((size_t)Nn * Nn * 2);        // 32MB
  unsigned short* htr4  = (unsigned short*)alloc((size_t)4 * 64 * Nn * 2);    // 2MB
  float* f14            = (float*)alloc((size_t)4 * Nn * 4);
  float* f24            = (float*)alloc((size_t)4 * Nn * 4);
  unsigned char* jb4    = (unsigned char*)alloc((size_t)4 * Nn);
  unsigned short* Mbuf  = (unsigned short*)alloc((size_t)4 * MC * Nn * 2);    // 6MB
  float* Hbuf           = (float*)alloc((size_t)8 * Nn * MC * 4 * 4);         // 96MB (max nh*SK*plane)
  unsigned short* att4  = (unsigned short*)alloc((size_t)4 * Nn * Nn * 2);    // 128MB
  float* cpart          = (float*)alloc((size_t)32 * Nn * 64 * 4);            // 32MB
  float* cat            = (float*)alloc((size_t)Nn * 256 * 4);                // 4MB
  float* x1             = (float*)alloc((size_t)Nn * 64 * 4);
  unsigned short* bth   = (unsigned short*)alloc((size_t)Nn * 64 * 2);
  unsigned short* btl   = (unsigned short*)alloc((size_t)Nn * 64 * 2);

  const size_t AS  = (size_t)Nn * Nn;        // att stride per head (ushort)
  const size_t BS  = (size_t)64 * Nn;        // htr stride per head (ushort)
  const size_t MS  = (size_t)MC * Nn;        // M stride per head (ushort)
  const size_t HS4 = (size_t)4 * Nn * MC;    // Hbuf per-head stride, nh=4 (SK=4)
  const size_t CS8 = (size_t)8 * Nn * 64;    // cpart per-head stride, nh=4 (SK=8)

  // one GAT pass over nh heads sharing adjbf
  auto run_stage = [&](const float* xin, int din, const float* Hm, size_t hms,
                       const float* av, size_t avs, int nh) {
    k_hf4<<<dim3(Nn / 4, nh), 256, 0, stream>>>(xin, din, Hm, hms, av, avs,
                                                htr4, f14, f24);
    k_mbuild<<<dim3(MC, nh), 256, 0, stream>>>(f14, f24, Mbuf, jb4);
    if (nh == 4) {
      // hist: SK=4, CG=3 (grid.y = 12)
      k_gemm<0, 64, false><<<dim3(32, 12, 4), 256, 0, stream>>>(
          adjbf, 0, Mbuf, nullptr, MS, Hbuf, HS4, MC, 3);
      k_sm<4><<<dim3(Nn), 256, 0, stream>>>(Hbuf, f24, jb4, att4, 4);
      // PV: SK=8
      k_gemm<0, 64, false><<<dim3(32, 8, 4), 256, 0, stream>>>(
          att4, AS, htr4, nullptr, BS, cpart, CS8, 64, 1);
    } else {
      // hist: SK=8, CG=3 (grid.y = 24)
      k_gemm<0, 64, false><<<dim3(32, 24, 1), 256, 0, stream>>>(
          adjbf, 0, Mbuf, nullptr, MS, Hbuf, 0, MC, 3);
      k_sm<8><<<dim3(Nn), 256, 0, stream>>>(Hbuf, f24, jb4, att4, 1);
      // PV: SK=32
      k_gemm<0, 64, false><<<dim3(32, 32, 1), 256, 0, stream>>>(
          att4, 0, htr4, nullptr, 0, cpart, 0, 64, 1);
    }
  };

  const float* prev = wini;
  for (int cell = 0; cell < 2; ++cell) {
    const float* adj_c = adj + (size_t)cell * Nn * Nn;
    k_cvt<<<dim3(Nn * Nn / 8 / 256), 256, 0, stream>>>(adj_c, adjbf);
    // 4 heads
    run_stage(prev, 64, hH + (size_t)cell * 4 * 64 * 64, (size_t)64 * 64,
              ha + (size_t)cell * 4 * 128, 128, 4);
    k_red4<64, 8><<<dim3(Nn * 64 / 256, 4), 256, 0, stream>>>(
        cpart, CS8, cat, 256, 0, 64, 1, nullptr, nullptr);
    // out-GAT
    run_stage(cat, 256, oH + (size_t)cell * 256 * 64, 0,
              oa + (size_t)cell * 128, 0, 1);
    if (cell == 0)
      k_red4<64, 32><<<dim3(Nn * 64 / 256, 1), 256, 0, stream>>>(
          cpart, 0, x1, 64, 0, 0, 1, nullptr, nullptr);
    else
      k_red4<64, 32><<<dim3(Nn * 64 / 256, 1), 256, 0, stream>>>(
          cpart, 0, nullptr, 0, 0, 0, 1, bth, btl);
    prev = x1;
  }

  // tail (cell 1 only; adjbf holds cell-1 adj in bf16)
  const float* x1c = x + (size_t)Nn * Nn;
  // t0 = x @ elu(x1)  (A f32 split hi/lo, B hi/lo planes)
  k_gemm<2, 64, true><<<dim3(32, 32, 1), 256, 0, stream>>>(
      x1c, 0, bth, btl, 0, cpart, 0, 64, 1);
  k_red4<64, 32><<<dim3(Nn * 64 / 256, 1), 256, 0, stream>>>(
      cpart, 0, nullptr, 0, 0, 0, 0, bth, nullptr);        // t0 -> bth
  // h1 = relu(adj1 @ t0); u = h1 @ l2w  (fused into k_redU)
  k_gemm<0, 64, false><<<dim3(32, 32, 1), 256, 0, stream>>>(
      adjbf, 0, bth, nullptr, 0, cpart, 0, 64, 1);
  k_redU<<<dim3(Nn / 4), 256, 0, stream>>>(
      cpart, l2w + 64 * 32, bth);                          // u -> bth[32][N]
  // h2 = adj1 @ u
  k_gemm<0, 32, false><<<dim3(32, 32, 1), 256, 0, stream>>>(
      adjbf, 0, bth, nullptr, 0, cpart, 0, 32, 1);
  k_red4<32, 32><<<dim3(Nn * 32 / 256, 1), 256, 0, stream>>>(
      cpart, 0, (float*)d_out, 32, 0, 0, 0, nullptr, nullptr);
}